// Round 1
// 292.443 us; speedup vs baseline: 1.0124x; 1.0124x over previous
//
#include <hip/hip_runtime.h>

// Problem constants (fixed by setup_inputs)
static constexpr int V  = 5;
static constexpr int B  = 2;
static constexpr int C  = 32;
static constexpr int H  = 256;
static constexpr int W  = 320;
static constexpr int CN = 4;
static constexpr int HW = H * W;
static constexpr int CG = 8;   // channels per group (per wave)
static constexpr int NG = 4;   // groups per block
static constexpr int XT = W / 64;        // 5 x-tiles

// ws layout: [0, 10.5MB) per-view partials (b,view,k,pix); then params
static constexpr size_t PARTIAL_FLOATS = (size_t)B * (V - 1) * CN * HW;
static constexpr size_t PARAMS_OFF     = PARTIAL_FLOATS;  // floats

static constexpr int FIN_NC = 4;  // channels per finalize block -> 160*8 = 1280 blocks

typedef float f32x2 __attribute__((ext_vector_type(2)));
typedef float f32x4 __attribute__((ext_vector_type(4)));

// Alignment-safe paired load (backend emits unaligned-capable dwordx2)
__device__ __forceinline__ f32x2 ld2(const float* p) {
    f32x2 v;
    __builtin_memcpy(&v, p, sizeof(f32x2));
    return v;
}

// ---------------------------------------------------------------------------
// Setup: per (b, src view i=1..4) compute proj = M_i @ inv(M_0) -> 12 floats
// ---------------------------------------------------------------------------
__global__ void setup_proj_kernel(const float* __restrict__ pm, float* __restrict__ params) {
    int b = threadIdx.x;
    if (b >= B) return;

    float M[V][16];
    for (int v = 0; v < V; ++v) {
        const float* E  = pm + ((size_t)(b * V + v) * 2 + 0) * 16;
        const float* Km = pm + ((size_t)(b * V + v) * 2 + 1) * 16;
        for (int r = 0; r < 3; ++r)
            for (int c = 0; c < 4; ++c) {
                float s = 0.f;
                for (int k = 0; k < 3; ++k) s += Km[r * 4 + k] * E[k * 4 + c];
                M[v][r * 4 + c] = s;
            }
        for (int c = 0; c < 4; ++c) M[v][12 + c] = E[12 + c];
    }

    float A[9], bb[3];
    for (int r = 0; r < 3; ++r) {
        for (int c = 0; c < 3; ++c) A[r * 3 + c] = M[0][r * 4 + c];
        bb[r] = M[0][r * 4 + 3];
    }
    float det = A[0] * (A[4] * A[8] - A[5] * A[7])
              - A[1] * (A[3] * A[8] - A[5] * A[6])
              + A[2] * (A[3] * A[7] - A[4] * A[6]);
    float id = 1.f / det;
    float Ai[9];
    Ai[0] = (A[4] * A[8] - A[5] * A[7]) * id;
    Ai[1] = (A[2] * A[7] - A[1] * A[8]) * id;
    Ai[2] = (A[1] * A[5] - A[2] * A[4]) * id;
    Ai[3] = (A[5] * A[6] - A[3] * A[8]) * id;
    Ai[4] = (A[0] * A[8] - A[2] * A[6]) * id;
    Ai[5] = (A[2] * A[3] - A[0] * A[5]) * id;
    Ai[6] = (A[3] * A[7] - A[4] * A[6]) * id;
    Ai[7] = (A[1] * A[6] - A[0] * A[7]) * id;
    Ai[8] = (A[0] * A[4] - A[1] * A[3]) * id;
    float bi[3];
    for (int r = 0; r < 3; ++r)
        bi[r] = -(Ai[r * 3 + 0] * bb[0] + Ai[r * 3 + 1] * bb[1] + Ai[r * 3 + 2] * bb[2]);

    float Minv[16];
    for (int r = 0; r < 3; ++r) {
        for (int c = 0; c < 3; ++c) Minv[r * 4 + c] = Ai[r * 3 + c];
        Minv[r * 4 + 3] = bi[r];
    }
    Minv[12] = 0.f; Minv[13] = 0.f; Minv[14] = 0.f; Minv[15] = 1.f;

    for (int v = 1; v < V; ++v) {
        float* dst = params + (size_t)(b * (V - 1) + (v - 1)) * 12;
        for (int r = 0; r < 3; ++r)
            for (int c = 0; c < 4; ++c) {
                float s = 0.f;
                for (int k = 0; k < 4; ++k) s += M[v][r * 4 + k] * Minv[k * 4 + c];
                dst[r * 4 + c] = s;
            }
    }
}

// ---------------------------------------------------------------------------
// Partial kernel: one block per (b, view, x-tile, y). Block = 64 px x 4 ch-grp.
// XCD slab swizzle: lid&7 -> (b,view). Inner loop batches 32 f32x2 loads
// (4 channels x 4 depths x 2 rows) before any FMA -> deep MLP per wave.
// ---------------------------------------------------------------------------
__global__ __launch_bounds__(256) void partial_kernel(
    const float* __restrict__ depth_values,   // (B,1,H,W)
    const float* __restrict__ features,       // (V,B,C,H,W)
    const float* __restrict__ depth_interval, // (B,1,H,W)
    const float* __restrict__ view_weights,   // (B,V-1,H,W)
    const float* __restrict__ params,         // (B,V-1,12)
    float* __restrict__ partial)              // (B,V-1,CN,HW)
{
    const int tid = threadIdx.x;
    const int p   = tid & 63;
    const int g   = tid >> 6;

    // slab swizzle
    const int lid = blockIdx.x + XT * (blockIdx.y + H * blockIdx.z);
    const int r   = lid & 7;          // one (b,view) per XCD residue
    const int q   = lid >> 3;         // x-then-y sweep
    const int b   = r >> 2;
    const int iv  = r & 3;            // view-1
    const int xt  = q % XT;
    const int y   = q / XT;

    const int x   = xt * 64 + p;
    const int pix = y * W + x;

    __shared__ float sp[12];
    __shared__ float sred[NG][CN][64];
    if (tid < 12) sp[tid] = params[(size_t)(b * (V - 1) + iv) * 12 + tid];
    __syncthreads();

    const float invd = 1.f / depth_values[(size_t)b * HW + pix];
    const float itv  = depth_interval[(size_t)b * HW + pix];
    const float low  = invd - (CN * 0.5f) * itv;
    const float step = (CN * itv) / (float)(CN - 1);
    float dep[CN];
#pragma unroll
    for (int k = 0; k < CN; ++k) dep[k] = 1.f / (low + (float)k * step);

    // this group's reference channels (read-once: nontemporal)
    const float* refp = features + ((size_t)b * C + g * CG) * HW + pix;
    float rf[CG];
#pragma unroll
    for (int c = 0; c < CG; ++c) rf[c] = __builtin_nontemporal_load(refp + (size_t)c * HW);

    const float fx = (float)x, fy = (float)y;
    const float rx = sp[0] * fx + sp[1] * fy + sp[2];
    const float ry = sp[4] * fx + sp[5] * fy + sp[6];
    const float rz = sp[8] * fx + sp[9] * fy + sp[10];
    const float tx = sp[3], ty = sp[7], tz = sp[11];

    const float* src = features + ((size_t)((iv + 1) * B + b) * C + g * CG) * HW;
    const float vw = view_weights[((size_t)b * (V - 1) + iv) * HW + pix];
    const float scale = vw * (1.f / (float)C);

    int   ib0[CN], ib1[CN];
    float wA0[CN], wB0[CN], wA1[CN], wB1[CN];
#pragma unroll
    for (int k = 0; k < CN; ++k) {
        const float d  = dep[k];
        const float px = rx * d + tx;
        const float py = ry * d + ty;
        const float pz = rz * d + tz;
        const float iz = 1.f / pz;
        const float gx = px * iz;
        const float gy = py * iz;

        const float x0f = floorf(gx), y0f = floorf(gy);
        const float wx1 = gx - x0f, wy1 = gy - y0f;
        const float wx0 = 1.f - wx1, wy0 = 1.f - wy1;
        const int x0 = (int)x0f, y0 = (int)y0f;
        const int x1 = x0 + 1, y1 = y0 + 1;

        const bool vx0 = (x0 >= 0) && (x0 <= W - 1);
        const bool vx1 = (x1 >= 0) && (x1 <= W - 1);
        const bool vy0 = (y0 >= 0) && (y0 <= H - 1);
        const bool vy1 = (y1 >= 0) && (y1 <= H - 1);

        const int cy0 = min(max(y0, 0), H - 1);
        const int cy1 = min(max(y1, 0), H - 1);
        const int bx  = min(max(x0, 0), W - 2);
        const int s   = x0 - bx;   // {-1, 0, 1} (else all weights 0)

        const float w00 = wx0 * wy0 * ((vx0 && vy0) ? scale : 0.f);
        const float w10 = wx1 * wy0 * ((vx1 && vy0) ? scale : 0.f);
        const float w01 = wx0 * wy1 * ((vx0 && vy1) ? scale : 0.f);
        const float w11 = wx1 * wy1 * ((vx1 && vy1) ? scale : 0.f);

        wA0[k] = (s == 0) ? w00 : ((s == -1) ? w10 : 0.f);
        wB0[k] = (s == 0) ? w10 : ((s == 1) ? w00 : 0.f);
        wA1[k] = (s == 0) ? w01 : ((s == -1) ? w11 : 0.f);
        wB1[k] = (s == 0) ? w11 : ((s == 1) ? w01 : 0.f);

        ib0[k] = cy0 * W + bx;
        ib1[k] = cy1 * W + bx;
    }

    float vol[CN] = {0.f, 0.f, 0.f, 0.f};
#pragma unroll
    for (int cc = 0; cc < CG; cc += 4) {
        // batch: 4 channels x 4 depths x 2 rows = 32 f32x2 loads in flight
        f32x2 P0[4][CN], P1[4][CN];
#pragma unroll
        for (int c = 0; c < 4; ++c) {
            const float* fc = src + (size_t)(cc + c) * HW;
#pragma unroll
            for (int k = 0; k < CN; ++k) {
                P0[c][k] = ld2(fc + ib0[k]);
                P1[c][k] = ld2(fc + ib1[k]);
            }
        }
#pragma unroll
        for (int c = 0; c < 4; ++c) {
            const float rfc = rf[cc + c];
#pragma unroll
            for (int k = 0; k < CN; ++k) {
                float t = wA0[k] * P0[c][k].x;
                t = fmaf(wB0[k], P0[c][k].y, t);
                t = fmaf(wA1[k], P1[c][k].x, t);
                t = fmaf(wB1[k], P1[c][k].y, t);
                vol[k] = fmaf(rfc, t, vol[k]);
            }
        }
    }

    // reduce across channel groups via LDS.
    // NG == CN == 4: group g reduces and stores plane k = g (all 256 threads
    // active in the epilogue instead of only g==0). Regular (cached) store so
    // finalize's reads hit L2/LLC, not HBM.
#pragma unroll
    for (int k = 0; k < CN; ++k) sred[g][k][p] = vol[k];
    __syncthreads();

    {
        const int k = g;
        float s = sred[0][k][p] + sred[1][k][p] + sred[2][k][p] + sred[3][k][p];
        float* dst = partial + ((size_t)(b * (V - 1) + iv) * CN + k) * HW + pix;
        *dst = s;
    }
}

// ---------------------------------------------------------------------------
// Finalize: sum 4 views' partials, normalize by wsum, broadcast to 128 planes.
// v2: channel-split grid. Each block covers 256 pixel-quads x FIN_NC channels.
// grid = (B*HW/1024, C/FIN_NC) = (160, 8) = 1280 blocks (~5/CU, 20 waves/CU)
// vs the old 160 blocks (<1/CU) that left the write BW at ~700 GB/s.
// partial+vw re-read 8x (105 MB total) but L2/LLC-resident (13 MB working set).
// Output stores stay nontemporal: 84 MB write-once, don't evict features L3.
// ---------------------------------------------------------------------------
__global__ __launch_bounds__(256) void finalize_kernel(
    const float* __restrict__ partial,       // (B,V-1,CN,HW)
    const float* __restrict__ view_weights,  // (B,V-1,H,W)
    float* __restrict__ out)                 // (B,C*CN,H,W)
{
    const int t   = blockIdx.x * 256 + threadIdx.x;
    const int idx = t * 4;                   // pixel quad (16B aligned)
    const int b   = idx / HW;
    const int pix = idx - b * HW;
    const int c0  = blockIdx.y * FIN_NC;

    f32x4 wsum = {1e-5f, 1e-5f, 1e-5f, 1e-5f};
#pragma unroll
    for (int i = 0; i < V - 1; ++i) {
        f32x4 vw = *(const f32x4*)(view_weights + ((size_t)b * (V - 1) + i) * HW + pix);
        wsum += vw;
    }
    const f32x4 iw = {1.f / wsum.x, 1.f / wsum.y, 1.f / wsum.z, 1.f / wsum.w};

    f32x4 sim[CN];
#pragma unroll
    for (int k = 0; k < CN; ++k) {
        f32x4 s = {0.f, 0.f, 0.f, 0.f};
#pragma unroll
        for (int i = 0; i < V - 1; ++i)
            s += *(const f32x4*)(partial + ((size_t)(b * (V - 1) + i) * CN + k) * HW + pix);
        sim[k] = s * iw;
    }

    float* op = out + (size_t)b * C * CN * HW + pix;
#pragma unroll
    for (int ci = 0; ci < FIN_NC; ++ci) {
        const int c = c0 + ci;
#pragma unroll
        for (int k = 0; k < CN; ++k)
            __builtin_nontemporal_store(sim[k], (f32x4*)(op + (size_t)(c * CN + k) * HW));
    }
}

extern "C" void kernel_launch(void* const* d_in, const int* in_sizes, int n_in,
                              void* d_out, int out_size, void* d_ws, size_t ws_size,
                              hipStream_t stream) {
    const float* depth_values   = (const float*)d_in[0];
    const float* features       = (const float*)d_in[1];
    const float* proj_matrices  = (const float*)d_in[2];
    const float* depth_interval = (const float*)d_in[3];
    const float* view_weights   = (const float*)d_in[7];
    float* out     = (float*)d_out;
    float* partial = (float*)d_ws;                 // 10.5 MB
    float* params  = (float*)d_ws + PARAMS_OFF;    // 96 floats

    setup_proj_kernel<<<1, B, 0, stream>>>(proj_matrices, params);

    dim3 grid1(XT, H, B * (V - 1));   // 10240 blocks, slab-swizzled inside
    partial_kernel<<<grid1, 256, 0, stream>>>(depth_values, features, depth_interval,
                                              view_weights, params, partial);

    dim3 grid2(B * HW / 1024, C / FIN_NC);   // (160, 8) = 1280 blocks
    finalize_kernel<<<grid2, 256, 0, stream>>>(partial, view_weights, out);
}

// Round 2
// 284.820 us; speedup vs baseline: 1.0395x; 1.0268x over previous
//
#include <hip/hip_runtime.h>

// Problem constants (fixed by setup_inputs)
static constexpr int V  = 5;
static constexpr int B  = 2;
static constexpr int C  = 32;
static constexpr int H  = 256;
static constexpr int W  = 320;
static constexpr int CN = 4;
static constexpr int HW = H * W;
static constexpr int CG = 8;   // channels per group (per wave)
static constexpr int NG = 4;   // groups per block
static constexpr int XT = W / 64;        // 5 x-tiles
static constexpr int NBLK = XT * H * B;  // 2560 fused blocks

// ws layout: params only now (96 floats)
static constexpr size_t PARAMS_OFF = 0;

typedef float f32x2 __attribute__((ext_vector_type(2)));
typedef float f32x4 __attribute__((ext_vector_type(4)));

// Alignment-safe paired load (backend emits unaligned-capable dwordx2)
__device__ __forceinline__ f32x2 ld2(const float* p) {
    f32x2 v;
    __builtin_memcpy(&v, p, sizeof(f32x2));
    return v;
}

// ---------------------------------------------------------------------------
// Setup: per (b, src view i=1..4) compute proj = M_i @ inv(M_0) -> 12 floats
// ---------------------------------------------------------------------------
__global__ void setup_proj_kernel(const float* __restrict__ pm, float* __restrict__ params) {
    int b = threadIdx.x;
    if (b >= B) return;

    float M[V][16];
    for (int v = 0; v < V; ++v) {
        const float* E  = pm + ((size_t)(b * V + v) * 2 + 0) * 16;
        const float* Km = pm + ((size_t)(b * V + v) * 2 + 1) * 16;
        for (int r = 0; r < 3; ++r)
            for (int c = 0; c < 4; ++c) {
                float s = 0.f;
                for (int k = 0; k < 3; ++k) s += Km[r * 4 + k] * E[k * 4 + c];
                M[v][r * 4 + c] = s;
            }
        for (int c = 0; c < 4; ++c) M[v][12 + c] = E[12 + c];
    }

    float A[9], bb[3];
    for (int r = 0; r < 3; ++r) {
        for (int c = 0; c < 3; ++c) A[r * 3 + c] = M[0][r * 4 + c];
        bb[r] = M[0][r * 4 + 3];
    }
    float det = A[0] * (A[4] * A[8] - A[5] * A[7])
              - A[1] * (A[3] * A[8] - A[5] * A[6])
              + A[2] * (A[3] * A[7] - A[4] * A[6]);
    float id = 1.f / det;
    float Ai[9];
    Ai[0] = (A[4] * A[8] - A[5] * A[7]) * id;
    Ai[1] = (A[2] * A[7] - A[1] * A[8]) * id;
    Ai[2] = (A[1] * A[5] - A[2] * A[4]) * id;
    Ai[3] = (A[5] * A[6] - A[3] * A[8]) * id;
    Ai[4] = (A[0] * A[8] - A[2] * A[6]) * id;
    Ai[5] = (A[2] * A[3] - A[0] * A[5]) * id;
    Ai[6] = (A[3] * A[7] - A[4] * A[6]) * id;
    Ai[7] = (A[1] * A[6] - A[0] * A[7]) * id;
    Ai[8] = (A[0] * A[4] - A[1] * A[3]) * id;
    float bi[3];
    for (int r = 0; r < 3; ++r)
        bi[r] = -(Ai[r * 3 + 0] * bb[0] + Ai[r * 3 + 1] * bb[1] + Ai[r * 3 + 2] * bb[2]);

    float Minv[16];
    for (int r = 0; r < 3; ++r) {
        for (int c = 0; c < 3; ++c) Minv[r * 4 + c] = Ai[r * 3 + c];
        Minv[r * 4 + 3] = bi[r];
    }
    Minv[12] = 0.f; Minv[13] = 0.f; Minv[14] = 0.f; Minv[15] = 1.f;

    for (int v = 1; v < V; ++v) {
        float* dst = params + (size_t)(b * (V - 1) + (v - 1)) * 12;
        for (int r = 0; r < 3; ++r)
            for (int c = 0; c < 4; ++c) {
                float s = 0.f;
                for (int k = 0; k < 4; ++k) s += M[v][r * 4 + k] * Minv[k * 4 + c];
                dst[r * 4 + c] = s;
            }
    }
}

// ---------------------------------------------------------------------------
// Fused kernel: one block per (b, y, x-tile). Block = 64 px x 4 ch-groups.
// Each thread accumulates volsum[k] over ALL 4 source views (per-view partials
// never materialized), LDS-reduces across channel groups, normalizes by the
// locally-computed wsum, then the whole block broadcast-writes the 128 output
// planes with regular (L2 write-combining) stores — no NT stores, no second
// kernel, no 10.5 MB partial round-trip.
// XCD swizzle: 2560 blocks -> 8 XCDs x 320; each XCD gets a contiguous
// 64-row slab of one batch (gather working set stays L2-local).
// ---------------------------------------------------------------------------
__global__ __launch_bounds__(256) void fused_kernel(
    const float* __restrict__ depth_values,   // (B,1,H,W)
    const float* __restrict__ features,       // (V,B,C,H,W)
    const float* __restrict__ depth_interval, // (B,1,H,W)
    const float* __restrict__ view_weights,   // (B,V-1,H,W)
    const float* __restrict__ params,         // (B,V-1,12)
    float* __restrict__ out)                  // (B,C*CN,H,W)
{
    const int tid = threadIdx.x;
    const int p   = tid & 63;
    const int g   = tid >> 6;

    // bijective XCD swizzle: NBLK % 8 == 0, chunk = 320
    const int d  = blockIdx.x;
    const int l  = (d & 7) * (NBLK / 8) + (d >> 3);
    const int xt = l % XT;
    const int r2 = l / XT;          // 0..511
    const int y  = r2 & (H - 1);
    const int b  = r2 >> 8;

    const int x   = xt * 64 + p;
    const int pix = y * W + x;

    __shared__ float sp4[48];                // 4 views x 12 params
    __shared__ float sred[NG][CN][64];       // cross-group reduce
    __shared__ float sim_lds[CN][64];        // normalized sim for store phase
    if (tid < 48) sp4[tid] = params[(size_t)b * 48 + tid];
    __syncthreads();

    const float invd = 1.f / depth_values[(size_t)b * HW + pix];
    const float itv  = depth_interval[(size_t)b * HW + pix];
    const float low  = invd - (CN * 0.5f) * itv;
    const float step = (CN * itv) / (float)(CN - 1);
    float dep[CN];
#pragma unroll
    for (int k = 0; k < CN; ++k) dep[k] = 1.f / (low + (float)k * step);

    // this group's reference channels: read exactly once globally -> NT load
    const float* refp = features + ((size_t)b * C + g * CG) * HW + pix;
    float rf[CG];
#pragma unroll
    for (int c = 0; c < CG; ++c) rf[c] = __builtin_nontemporal_load(refp + (size_t)c * HW);

    const float fx = (float)x, fy = (float)y;

    float volsum[CN] = {0.f, 0.f, 0.f, 0.f};
    float wsum = 1e-5f;

    for (int iv = 0; iv < V - 1; ++iv) {
        const float* spv = &sp4[iv * 12];
        const float rx = spv[0] * fx + spv[1] * fy + spv[2];
        const float ry = spv[4] * fx + spv[5] * fy + spv[6];
        const float rz = spv[8] * fx + spv[9] * fy + spv[10];
        const float tx = spv[3], ty = spv[7], tz = spv[11];

        const float vw = view_weights[((size_t)b * (V - 1) + iv) * HW + pix];
        wsum += vw;
        const float scale = vw * (1.f / (float)C);

        const float* src = features + ((size_t)((iv + 1) * B + b) * C + g * CG) * HW;

        int   ib0[CN], ib1[CN];
        float wA0[CN], wB0[CN], wA1[CN], wB1[CN];
#pragma unroll
        for (int k = 0; k < CN; ++k) {
            const float dd = dep[k];
            const float px = rx * dd + tx;
            const float py = ry * dd + ty;
            const float pz = rz * dd + tz;
            const float iz = 1.f / pz;
            const float gx = px * iz;
            const float gy = py * iz;

            const float x0f = floorf(gx), y0f = floorf(gy);
            const float wx1 = gx - x0f, wy1 = gy - y0f;
            const float wx0 = 1.f - wx1, wy0 = 1.f - wy1;
            const int x0 = (int)x0f, y0 = (int)y0f;
            const int x1 = x0 + 1, y1 = y0 + 1;

            const bool vx0 = (x0 >= 0) && (x0 <= W - 1);
            const bool vx1 = (x1 >= 0) && (x1 <= W - 1);
            const bool vy0 = (y0 >= 0) && (y0 <= H - 1);
            const bool vy1 = (y1 >= 0) && (y1 <= H - 1);

            const int cy0 = min(max(y0, 0), H - 1);
            const int cy1 = min(max(y1, 0), H - 1);
            const int bx  = min(max(x0, 0), W - 2);
            const int s   = x0 - bx;   // {-1, 0, 1} (else all weights 0)

            const float w00 = wx0 * wy0 * ((vx0 && vy0) ? scale : 0.f);
            const float w10 = wx1 * wy0 * ((vx1 && vy0) ? scale : 0.f);
            const float w01 = wx0 * wy1 * ((vx0 && vy1) ? scale : 0.f);
            const float w11 = wx1 * wy1 * ((vx1 && vy1) ? scale : 0.f);

            wA0[k] = (s == 0) ? w00 : ((s == -1) ? w10 : 0.f);
            wB0[k] = (s == 0) ? w10 : ((s == 1) ? w00 : 0.f);
            wA1[k] = (s == 0) ? w01 : ((s == -1) ? w11 : 0.f);
            wB1[k] = (s == 0) ? w11 : ((s == 1) ? w01 : 0.f);

            ib0[k] = cy0 * W + bx;
            ib1[k] = cy1 * W + bx;
        }

#pragma unroll
        for (int cc = 0; cc < CG; cc += 4) {
            // batch: 4 channels x 4 depths x 2 rows = 32 f32x2 loads in flight
            f32x2 P0[4][CN], P1[4][CN];
#pragma unroll
            for (int c = 0; c < 4; ++c) {
                const float* fc = src + (size_t)(cc + c) * HW;
#pragma unroll
                for (int k = 0; k < CN; ++k) {
                    P0[c][k] = ld2(fc + ib0[k]);
                    P1[c][k] = ld2(fc + ib1[k]);
                }
            }
#pragma unroll
            for (int c = 0; c < 4; ++c) {
                const float rfc = rf[cc + c];
#pragma unroll
                for (int k = 0; k < CN; ++k) {
                    float t = wA0[k] * P0[c][k].x;
                    t = fmaf(wB0[k], P0[c][k].y, t);
                    t = fmaf(wA1[k], P1[c][k].x, t);
                    t = fmaf(wB1[k], P1[c][k].y, t);
                    volsum[k] = fmaf(rfc, t, volsum[k]);
                }
            }
        }
    }

    // cross-group reduce + normalize (NG == CN: group g owns depth k = g)
#pragma unroll
    for (int k = 0; k < CN; ++k) sred[g][k][p] = volsum[k];
    __syncthreads();

    {
        const int k = g;
        const float s = sred[0][k][p] + sred[1][k][p] + sred[2][k][p] + sred[3][k][p];
        sim_lds[k][p] = s * (1.f / wsum);   // every thread has wsum for its px
    }
    __syncthreads();

    // broadcast-write 128 planes x 64 px (32 KB) with regular cached stores.
    // thread: quad = tid&15 (4-px f32x4), pc = tid>>4; 8 planes per thread.
    {
        const int quad = tid & 15;
        const int pc   = tid >> 4;
        float* op = out + (size_t)b * C * CN * HW + y * W + xt * 64 + quad * 4;
#pragma unroll
        for (int j = 0; j < 8; ++j) {
            const int plane = pc * 8 + j;          // 0..127, each exactly once
            const int k     = plane & 3;           // == j & 3
            const f32x4 v   = *(const f32x4*)&sim_lds[k][quad * 4];
            *(f32x4*)(op + (size_t)plane * HW) = v;
        }
    }
}

extern "C" void kernel_launch(void* const* d_in, const int* in_sizes, int n_in,
                              void* d_out, int out_size, void* d_ws, size_t ws_size,
                              hipStream_t stream) {
    const float* depth_values   = (const float*)d_in[0];
    const float* features       = (const float*)d_in[1];
    const float* proj_matrices  = (const float*)d_in[2];
    const float* depth_interval = (const float*)d_in[3];
    const float* view_weights   = (const float*)d_in[7];
    float* out    = (float*)d_out;
    float* params = (float*)d_ws + PARAMS_OFF;    // 96 floats

    setup_proj_kernel<<<1, B, 0, stream>>>(proj_matrices, params);

    fused_kernel<<<NBLK, 256, 0, stream>>>(depth_values, features, depth_interval,
                                           view_weights, params, out);
}